// Round 20
// baseline (118.258 us; speedup 1.0000x reference)
//
#include <hip/hip_runtime.h>

#define B_   64
#define H_   128
#define W_   2048
#define HW_  (H_ * W_)        // 262144
#define OH_  128
#define OW_  2048

typedef float nfloat4 __attribute__((ext_vector_type(4)));
typedef float f2v __attribute__((ext_vector_type(2), aligned(4)));

// OpenBLAS sgemm emulation — SkylakeX params (VERIFIED bit-exact in round 6):
//   SGEMM_DEFAULT_Q = 320; K = 262144 -> blocks 0..817 len 320,
//   blk 818: off 261760 len 192; blk 819: off 261952 len 192.
//   Per C element: single sequential FMA chain over k within each block;
//   cross-block C += S_blk ascending; + b_loc in fp32.
// !!! The per-(blk,b,j) fmaf sequence and the K2 fp32 replay are bit-locked —
// !!! optimizations may only change load mechanics / parallel mapping.
#define QBLK 320
#define NBLK 820

// d_out scratch layout (fully overwritten by K2 at the end):
//   part: [0 .. 820*384)               = 1.26 MB
//   wT  : [WT_OFF .. WT_OFF + 6*HW_)   = 6.3 MB  (wT[j][k] = w[k*6+j])
#define WT_OFF (1u << 21)   // 8 MB offset

__device__ __forceinline__ int blk_off(int blk) {
    if (blk <= 818) return blk * QBLK;    // 818*320 = 261760
    return 261952;                        // blk 819
}
__device__ __forceinline__ int blk_len(int blk) {
    return (blk < 818) ? 320 : 192;
}

// ---------------------------------------------------------------------------
// K0: w transpose via LDS (round-15, measured ~2.5 us). Reads coalesced;
// writes 6 segments of 64 consecutive floats.
// ---------------------------------------------------------------------------
__global__ __launch_bounds__(384)
void st_wtrans(const float* __restrict__ w, float* __restrict__ wT)
{
    __shared__ float t[384];
    const int g   = blockIdx.x;          // 0 .. HW_/64-1
    const int tid = threadIdx.x;
    t[tid] = w[(size_t)g * 384 + tid];
    __syncthreads();
    const int j  = tid >> 6;             // 0..5
    const int kk = tid & 63;
    wT[(size_t)j * HW_ + g * 64 + kk] = t[kk * 6 + j];
}

// ---------------------------------------------------------------------------
// K1 (round-20): BARRIER-FREE STREAMING WAVES.
// r17-r19 showed the LDS-panel structure convoys (stage->barrier->compute,
// <=3 blocks/CU); dbuf was neutral. New shape: one wave per (kblk, 8-row
// group); lane = (j = lane>>3 in 0..5, brow = lane&7); lanes 48-63 idle.
//  - x: per-lane float4 stream; the 6 j-lanes of a row share ONE address ->
//    VMEM merges them (x read once, 8 lines per load instr).
//  - w: wT[j] float4 stream, 6 distinct addresses/load, L1/L2-hot.
//  - no LDS, no barrier; 6560 single-wave blocks (~25 waves/CU) keep loads
//    in flight continuously; compiler pipelines via counted vmcnt.
// Chain = exact k-ascending fmaf sequence of the verified round-6 kernel.
// part layout: [kblk][b*6+j].
// ---------------------------------------------------------------------------
__global__ __launch_bounds__(64)
void st_block_sums(const float* __restrict__ x, const float* __restrict__ wT,
                   float* __restrict__ part)
{
    const int task = blockIdx.x;          // 0..6559
    const int kblk = task >> 3;
    const int grp  = task & 7;            // 8-row batch group
    const int lane = threadIdx.x;

    const int off = blk_off(kblk);
    const int nt4 = blk_len(kblk) >> 2;   // 80 or 48

    const int j    = lane >> 3;           // 0..7 (6,7 idle)
    const int brow = lane & 7;
    const int b    = grp * 8 + brow;

    if (j >= 6) return;                   // exec-mask idle lanes (no barrier)

    const float4* __restrict__ xr = (const float4*)(x + (size_t)b * HW_ + off);
    const float4* __restrict__ wr = (const float4*)(wT + (size_t)j * HW_ + off);

    float a = 0.f;
    if (nt4 == 80) {
#pragma unroll 16
        for (int t4 = 0; t4 < 80; ++t4) {
            const float4 xv = xr[t4];
            const float4 wv = wr[t4];
            a = fmaf(xv.x, wv.x, a);
            a = fmaf(xv.y, wv.y, a);
            a = fmaf(xv.z, wv.z, a);
            a = fmaf(xv.w, wv.w, a);
        }
    } else {
#pragma unroll 16
        for (int t4 = 0; t4 < 48; ++t4) {
            const float4 xv = xr[t4];
            const float4 wv = wr[t4];
            a = fmaf(xv.x, wv.x, a);
            a = fmaf(xv.y, wv.y, a);
            a = fmaf(xv.z, wv.z, a);
            a = fmaf(xv.w, wv.w, a);
        }
    }

    part[(size_t)kblk * 384 + (size_t)b * 6 + j] = a;
}

// ---------------------------------------------------------------------------
// K1b (round-17, unchanged): ordered cross-block accumulation, latency-
// batched (64-wide register rounds; add order identical -> bit-exact).
// ---------------------------------------------------------------------------
__global__ __launch_bounds__(64)
void st_theta_final(const float* __restrict__ part, const float* __restrict__ bl,
                    float* __restrict__ theta)
{
#pragma clang fp contract(off)
    const int i = blockIdx.x * 64 + threadIdx.x;   // 0..383
    const int j = i % 6;
    const float* __restrict__ p = part + i;        // stride 384 per kblk

    float acc;
    {
        float r[64];
#pragma unroll
        for (int u = 0; u < 64; ++u) r[u] = p[(size_t)u * 384];
        acc = r[0];
#pragma unroll
        for (int u = 1; u < 64; ++u) acc = acc + r[u];
    }
    for (int base = 64; base < 768; base += 64) {
        float r[64];
#pragma unroll
        for (int u = 0; u < 64; ++u) r[u] = p[(size_t)(base + u) * 384];
#pragma unroll
        for (int u = 0; u < 64; ++u) acc = acc + r[u];
    }
    {
        float r[52];
#pragma unroll
        for (int u = 0; u < 52; ++u) r[u] = p[(size_t)(768 + u) * 384];
#pragma unroll
        for (int u = 0; u < 52; ++u) acc = acc + r[u];
    }
    theta[i] = acc + bl[j];
}

// ---------------------------------------------------------------------------
// K2 (round-16, unchanged): bilinear sampler — faithful fp32 numpy replay.
// Float-domain clip via v_med3_f32; divergence-free float2 loads + cndmask.
// ---------------------------------------------------------------------------
__global__ __launch_bounds__(256)
void st_sample(const float* __restrict__ x, const float* __restrict__ theta,
               float* __restrict__ out)
{
#pragma clang fp contract(off)
    __shared__ float th[6];
    const int blk = blockIdx.x;
    const int b   = blk >> 8;          // 256 blocks per batch
    const int rem = blk & 255;
    const int yo  = rem >> 1;
    const int seg = rem & 1;

    if (threadIdx.x < 6) th[threadIdx.x] = theta[b * 6 + threadIdx.x];
    __syncthreads();

    const float t00 = th[0], t01 = th[1], t02 = th[2];
    const float t10 = th[3], t11 = th[4], t12 = th[5];

    const int xo0 = seg * 1024 + threadIdx.x * 4;
    const float* __restrict__ img = x + (size_t)b * HW_;
    const float yof = (float)yo;

    const float cx1 = t01 * yof;
    const float cy1 = t11 * yof;

    nfloat4 o;
#pragma unroll
    for (int i = 0; i < 4; ++i) {
        const float xof = (float)(xo0 + i);
        const float px  = t00 * xof;
        const float sx  = px + cx1;
        const float xq  = sx + t02;
        const float py  = t10 * xof;
        const float sy  = py + cy1;
        const float yq  = sy + t12;

        const float xf0 = floorf(xq);
        const float yf0 = floorf(yq);

        const float x0f = __builtin_amdgcn_fmed3f(xf0,        0.f, 2047.f);
        const float x1f = __builtin_amdgcn_fmed3f(xf0 + 1.0f, 0.f, 2047.f);
        const float y0f = __builtin_amdgcn_fmed3f(yf0,        0.f,  127.f);
        const float y1f = __builtin_amdgcn_fmed3f(yf0 + 1.0f, 0.f,  127.f);

        const float basef = fminf(x0f, 2046.0f);
        const int base_i = (int)basef;
        const int y0c    = (int)y0f;
        const int y1c    = (int)y1f;

        const f2v v0 = *(const f2v*)(img + y0c * W_ + base_i);
        const f2v v1 = *(const f2v*)(img + y1c * W_ + base_i);

        const bool hiA = (x0f == 2047.0f);   // right clamp
        const bool loC = (x1f == basef);     // left clamp
        const float Ia = hiA ? v0.y : v0.x;
        const float Ic = loC ? v0.x : v0.y;
        const float Ib = hiA ? v1.y : v1.x;
        const float Id = loC ? v1.x : v1.y;

        const float gx = x1f - xq;
        const float fx = xq - x0f;
        const float gy = y1f - yq;
        const float fy = yq - y0f;

        const float wa = gx * gy;
        const float wb = gx * fy;
        const float wc = fx * gy;
        const float wd = fx * fy;

        const float pa = wa * Ia;
        const float pb = wb * Ib;
        const float s1 = pa + pb;
        const float pc = wc * Ic;
        const float s2 = s1 + pc;
        const float pd = wd * Id;
        o[i] = s2 + pd;
    }

    const size_t oidx = ((size_t)b * OH_ + yo) * OW_ + xo0;
    __builtin_nontemporal_store(o, (nfloat4*)(out + oidx));
}

extern "C" void kernel_launch(void* const* d_in, const int* in_sizes, int n_in,
                              void* d_out, int out_size, void* d_ws, size_t ws_size,
                              hipStream_t stream)
{
    const float* x  = (const float*)d_in[0];
    const float* w  = (const float*)d_in[1];
    const float* bl = (const float*)d_in[2];
    float* out = (float*)d_out;

    // d_out doubles as scratch (part @0, wT @WT_OFF), fully consumed before
    // st_sample overwrites everything.
    float* part  = (float*)d_out;
    float* wT    = (float*)d_out + WT_OFF;
    float* theta = (float*)d_ws;    // 384 floats

    st_wtrans<<<HW_ / 64, 384, 0, stream>>>(w, wT);
    st_block_sums<<<NBLK * 8, 64, 0, stream>>>(x, wT, part);
    st_theta_final<<<6, 64, 0, stream>>>(part, bl, theta);
    st_sample<<<B_ * OH_ * 2, 256, 0, stream>>>(x, theta, out);
}

// Round 21
// 81.001 us; speedup vs baseline: 1.4600x; 1.4600x over previous
//
#include <hip/hip_runtime.h>

#define B_   64
#define H_   128
#define W_   2048
#define HW_  (H_ * W_)        // 262144
#define OH_  128
#define OW_  2048

typedef float nfloat4 __attribute__((ext_vector_type(4)));
typedef float f2v __attribute__((ext_vector_type(2), aligned(4)));

// OpenBLAS sgemm emulation — SkylakeX params (VERIFIED bit-exact in round 6):
//   SGEMM_DEFAULT_Q = 320; K = 262144 -> blocks 0..817 len 320,
//   blk 818: off 261760 len 192; blk 819: off 261952 len 192.
//   Per C element: single sequential FMA chain over k within each block;
//   cross-block C += S_blk ascending; + b_loc in fp32.
// !!! The per-(blk,b,j) fmaf sequence and the K2 fp32 replay are bit-locked —
// !!! optimizations may only change load mechanics / parallel mapping.
#define QBLK 320
#define NBLK 820

__device__ __forceinline__ int blk_off(int blk) {
    if (blk <= 818) return blk * QBLK;    // 818*320 = 261760
    return 261952;                        // blk 819
}
__device__ __forceinline__ int blk_len(int blk) {
    return (blk < 818) ? 320 : 192;
}

// ---------------------------------------------------------------------------
// K1 (round-17 exact — best measured variant, ~33 us; r18/r19/r20 structural
// alternatives all neutral-to-worse, see journal):
// 1640 blocks x 192 thr; block = (kblk, 32-row half); thread = (j, b).
// x staged via global_load_lds w=16 into stride-81 rows (81 == 1 mod 8:
// bank-group spread, conflict-light); w reg-batched -> transposed LDS.
// Chain = exact k-ascending fmaf sequence. part layout: [kblk][b*6+j].
// ---------------------------------------------------------------------------
#define XSTR 81
__global__ __launch_bounds__(192)
void st_block_sums(const float* __restrict__ x, const float* __restrict__ w,
                   float* __restrict__ part)
{
    __shared__ float4 xs4[32 * XSTR];    // 41472 B
    __shared__ float  wt[6 * QBLK];      //  7680 B  (48.0 KB total)
    const int kblk = blockIdx.x >> 1;
    const int half = blockIdx.x & 1;
    const int tid  = threadIdx.x;

    const int off = blk_off(kblk);
    const int len = blk_len(kblk);       // 320 or 192
    const int nt4 = len >> 2;            // 80 or 48
    const int b0  = half * 32;

    const int widx = tid >> 6;           // wave 0..2
    const int lane = tid & 63;

#pragma unroll
    for (int i = 0; i < 14; ++i) {
        const int base = i * 192 + widx * 64;     // wave-uniform slot base
        if (base < 32 * XSTR) {                   // uniform per wave
            const int idx = base + lane;
            if (idx < 32 * XSTR) {                // EXEC mask (last chunk)
                const int r  = idx / XSTR;
                const int f4 = idx % XSTR;
                const int ug = (f4 < nt4) ? f4 : 0;   // pad -> harmless src
                const float* gp = x + (size_t)(b0 + r) * HW_ + off + ug * 4;
                __builtin_amdgcn_global_load_lds(
                    (const __attribute__((address_space(1))) unsigned int*)gp,
                    (__attribute__((address_space(3))) unsigned int*)&xs4[base],
                    16, 0, 0);
            }
        }
    }

    float wreg[10];
#pragma unroll
    for (int i = 0; i < 10; ++i) {
        const int e = tid + i * 192;
        wreg[i] = (e < 6 * len) ? w[(size_t)off * 6 + e] : 0.f;
    }
#pragma unroll
    for (int i = 0; i < 10; ++i) {
        const int e = tid + i * 192;
        if (e < 6 * len) wt[(e % 6) * QBLK + (e / 6)] = wreg[i];
    }
    __syncthreads();   // drains global_load_lds (vmcnt) + ds_writes

    const int j = tid >> 5;              // 0..5 (2 j per wave)
    const int b = tid & 31;              // row within half

    const float4* __restrict__ xr = xs4 + b * XSTR;
    const float*  __restrict__ wr = wt + j * QBLK;

    float a = 0.f;
    if (nt4 == 80) {
#pragma unroll
        for (int t4 = 0; t4 < 80; ++t4) {
            const float4 xv = xr[t4];
            const float4 wv = *(const float4*)(wr + t4 * 4);
            a = fmaf(xv.x, wv.x, a);
            a = fmaf(xv.y, wv.y, a);
            a = fmaf(xv.z, wv.z, a);
            a = fmaf(xv.w, wv.w, a);
        }
    } else {
#pragma unroll
        for (int t4 = 0; t4 < 48; ++t4) {
            const float4 xv = xr[t4];
            const float4 wv = *(const float4*)(wr + t4 * 4);
            a = fmaf(xv.x, wv.x, a);
            a = fmaf(xv.y, wv.y, a);
            a = fmaf(xv.z, wv.z, a);
            a = fmaf(xv.w, wv.w, a);
        }
    }

    part[(size_t)kblk * 384 + (size_t)(b0 + b) * 6 + j] = a;
}

// ---------------------------------------------------------------------------
// K1b (round-17, unchanged): ordered cross-block accumulation, latency-
// batched (64-wide register rounds; add order identical -> bit-exact).
// ---------------------------------------------------------------------------
__global__ __launch_bounds__(64)
void st_theta_final(const float* __restrict__ part, const float* __restrict__ bl,
                    float* __restrict__ theta)
{
#pragma clang fp contract(off)
    const int i = blockIdx.x * 64 + threadIdx.x;   // 0..383
    const int j = i % 6;
    const float* __restrict__ p = part + i;        // stride 384 per kblk

    float acc;
    {
        float r[64];
#pragma unroll
        for (int u = 0; u < 64; ++u) r[u] = p[(size_t)u * 384];
        acc = r[0];
#pragma unroll
        for (int u = 1; u < 64; ++u) acc = acc + r[u];
    }
    for (int base = 64; base < 768; base += 64) {
        float r[64];
#pragma unroll
        for (int u = 0; u < 64; ++u) r[u] = p[(size_t)(base + u) * 384];
#pragma unroll
        for (int u = 0; u < 64; ++u) acc = acc + r[u];
    }
    {
        float r[52];
#pragma unroll
        for (int u = 0; u < 52; ++u) r[u] = p[(size_t)(768 + u) * 384];
#pragma unroll
        for (int u = 0; u < 52; ++u) acc = acc + r[u];
    }
    theta[i] = acc + bl[j];
}

// ---------------------------------------------------------------------------
// K2 (round-21): 8 px/thread, block = one output row (256 thr x 8 = 2048).
// theta read via block-uniform pointer -> s_load into SGPRs (no LDS, no
// barrier; SMEM lgkm harmless here — no ds_reads in this kernel).
// Per-px fp32 replay byte-identical to round 16 (med3 clip, float2 loads,
// cndmask select, numpy-order blend, contract off).
// ---------------------------------------------------------------------------
__global__ __launch_bounds__(256)
void st_sample(const float* __restrict__ x, const float* __restrict__ theta,
               float* __restrict__ out)
{
#pragma clang fp contract(off)
    const int blk = blockIdx.x;          // 0..8191 = b*128 + yo
    const int b   = blk >> 7;
    const int yo  = blk & 127;

    const float* __restrict__ tp = theta + b * 6;   // block-uniform -> s_load
    const float t00 = tp[0], t01 = tp[1], t02 = tp[2];
    const float t10 = tp[3], t11 = tp[4], t12 = tp[5];

    const int xo0 = threadIdx.x * 8;
    const float* __restrict__ img = x + (size_t)b * HW_;
    const float yof = (float)yo;

    const float cx1 = t01 * yof;
    const float cy1 = t11 * yof;

    float ov[8];
#pragma unroll
    for (int i = 0; i < 8; ++i) {
        const float xof = (float)(xo0 + i);
        const float px  = t00 * xof;
        const float sx  = px + cx1;
        const float xq  = sx + t02;
        const float py  = t10 * xof;
        const float sy  = py + cy1;
        const float yq  = sy + t12;

        const float xf0 = floorf(xq);
        const float yf0 = floorf(yq);

        const float x0f = __builtin_amdgcn_fmed3f(xf0,        0.f, 2047.f);
        const float x1f = __builtin_amdgcn_fmed3f(xf0 + 1.0f, 0.f, 2047.f);
        const float y0f = __builtin_amdgcn_fmed3f(yf0,        0.f,  127.f);
        const float y1f = __builtin_amdgcn_fmed3f(yf0 + 1.0f, 0.f,  127.f);

        const float basef = fminf(x0f, 2046.0f);
        const int base_i = (int)basef;
        const int y0c    = (int)y0f;
        const int y1c    = (int)y1f;

        const f2v v0 = *(const f2v*)(img + y0c * W_ + base_i);
        const f2v v1 = *(const f2v*)(img + y1c * W_ + base_i);

        const bool hiA = (x0f == 2047.0f);   // right clamp
        const bool loC = (x1f == basef);     // left clamp
        const float Ia = hiA ? v0.y : v0.x;
        const float Ic = loC ? v0.x : v0.y;
        const float Ib = hiA ? v1.y : v1.x;
        const float Id = loC ? v1.x : v1.y;

        const float gx = x1f - xq;
        const float fx = xq - x0f;
        const float gy = y1f - yq;
        const float fy = yq - y0f;

        const float wa = gx * gy;
        const float wb = gx * fy;
        const float wc = fx * gy;
        const float wd = fx * fy;

        const float pa = wa * Ia;
        const float pb = wb * Ib;
        const float s1 = pa + pb;
        const float pc = wc * Ic;
        const float s2 = s1 + pc;
        const float pd = wd * Id;
        ov[i] = s2 + pd;
    }

    nfloat4 o0, o1;
    o0[0] = ov[0]; o0[1] = ov[1]; o0[2] = ov[2]; o0[3] = ov[3];
    o1[0] = ov[4]; o1[1] = ov[5]; o1[2] = ov[6]; o1[3] = ov[7];

    const size_t oidx = ((size_t)b * OH_ + yo) * OW_ + xo0;
    __builtin_nontemporal_store(o0, (nfloat4*)(out + oidx));
    __builtin_nontemporal_store(o1, (nfloat4*)(out + oidx + 4));
}

extern "C" void kernel_launch(void* const* d_in, const int* in_sizes, int n_in,
                              void* d_out, int out_size, void* d_ws, size_t ws_size,
                              hipStream_t stream)
{
    const float* x  = (const float*)d_in[0];
    const float* w  = (const float*)d_in[1];
    const float* bl = (const float*)d_in[2];
    float* out = (float*)d_out;

    // d_out doubles as the 1.26 MB block-sum scratch (820*384 floats), fully
    // consumed by st_theta_final before st_sample overwrites every element.
    float* part  = (float*)d_out;
    float* theta = (float*)d_ws;    // 384 floats

    st_block_sums<<<NBLK * 2, 192, 0, stream>>>(x, w, part);
    st_theta_final<<<6, 64, 0, stream>>>(part, bl, theta);
    st_sample<<<B_ * OH_, 256, 0, stream>>>(x, theta, out);
}

// Round 22
// 68.018 us; speedup vs baseline: 1.7386x; 1.1909x over previous
//
#include <hip/hip_runtime.h>

#define B_   64
#define H_   128
#define W_   2048
#define HW_  (H_ * W_)        // 262144
#define OH_  128
#define OW_  2048

typedef float nfloat4 __attribute__((ext_vector_type(4)));
typedef float f2v __attribute__((ext_vector_type(2), aligned(4)));

// OpenBLAS sgemm emulation — SkylakeX params (VERIFIED bit-exact in round 6):
//   SGEMM_DEFAULT_Q = 320; K = 262144 -> blocks 0..817 len 320,
//   blk 818: off 261760 len 192; blk 819: off 261952 len 192.
//   Per C element: single sequential FMA chain over k within each block;
//   cross-block C += S_blk ascending; + b_loc in fp32.
// !!! The per-(blk,b,j) fmaf sequence and the K2 fp32 replay are bit-locked —
// !!! optimizations may only change load mechanics / parallel mapping.
#define QBLK 320
#define NBLK 820

__device__ __forceinline__ int blk_off(int blk) {
    if (blk <= 818) return blk * QBLK;    // 818*320 = 261760
    return 261952;                        // blk 819
}
__device__ __forceinline__ int blk_len(int blk) {
    return (blk < 818) ? 320 : 192;
}

// ---------------------------------------------------------------------------
// K1 (round-17 exact — best measured variant, ~33 us across 7 structural
// alternatives: r8 reg-chains 45, r10 1-wave 91, r11 streaming 74, r12 47,
// r14 SMEM-w 43, r18 quarter-blocks 38, r19 dbuf 33-neutral, r20 barrier-
// free streaming 68):
// 1640 blocks x 192 thr; block = (kblk, 32-row half); thread = (j, b).
// x staged via global_load_lds w=16 into stride-81 rows (81 == 1 mod 8:
// bank-group spread, conflict-light); w reg-batched -> transposed LDS.
// Chain = exact k-ascending fmaf sequence. part layout: [kblk][b*6+j].
// ---------------------------------------------------------------------------
#define XSTR 81
__global__ __launch_bounds__(192)
void st_block_sums(const float* __restrict__ x, const float* __restrict__ w,
                   float* __restrict__ part)
{
    __shared__ float4 xs4[32 * XSTR];    // 41472 B
    __shared__ float  wt[6 * QBLK];      //  7680 B  (48.0 KB total)
    const int kblk = blockIdx.x >> 1;
    const int half = blockIdx.x & 1;
    const int tid  = threadIdx.x;

    const int off = blk_off(kblk);
    const int len = blk_len(kblk);       // 320 or 192
    const int nt4 = len >> 2;            // 80 or 48
    const int b0  = half * 32;

    const int widx = tid >> 6;           // wave 0..2
    const int lane = tid & 63;

#pragma unroll
    for (int i = 0; i < 14; ++i) {
        const int base = i * 192 + widx * 64;     // wave-uniform slot base
        if (base < 32 * XSTR) {                   // uniform per wave
            const int idx = base + lane;
            if (idx < 32 * XSTR) {                // EXEC mask (last chunk)
                const int r  = idx / XSTR;
                const int f4 = idx % XSTR;
                const int ug = (f4 < nt4) ? f4 : 0;   // pad -> harmless src
                const float* gp = x + (size_t)(b0 + r) * HW_ + off + ug * 4;
                __builtin_amdgcn_global_load_lds(
                    (const __attribute__((address_space(1))) unsigned int*)gp,
                    (__attribute__((address_space(3))) unsigned int*)&xs4[base],
                    16, 0, 0);
            }
        }
    }

    float wreg[10];
#pragma unroll
    for (int i = 0; i < 10; ++i) {
        const int e = tid + i * 192;
        wreg[i] = (e < 6 * len) ? w[(size_t)off * 6 + e] : 0.f;
    }
#pragma unroll
    for (int i = 0; i < 10; ++i) {
        const int e = tid + i * 192;
        if (e < 6 * len) wt[(e % 6) * QBLK + (e / 6)] = wreg[i];
    }
    __syncthreads();   // drains global_load_lds (vmcnt) + ds_writes

    const int j = tid >> 5;              // 0..5 (2 j per wave)
    const int b = tid & 31;              // row within half

    const float4* __restrict__ xr = xs4 + b * XSTR;
    const float*  __restrict__ wr = wt + j * QBLK;

    float a = 0.f;
    if (nt4 == 80) {
#pragma unroll
        for (int t4 = 0; t4 < 80; ++t4) {
            const float4 xv = xr[t4];
            const float4 wv = *(const float4*)(wr + t4 * 4);
            a = fmaf(xv.x, wv.x, a);
            a = fmaf(xv.y, wv.y, a);
            a = fmaf(xv.z, wv.z, a);
            a = fmaf(xv.w, wv.w, a);
        }
    } else {
#pragma unroll
        for (int t4 = 0; t4 < 48; ++t4) {
            const float4 xv = xr[t4];
            const float4 wv = *(const float4*)(wr + t4 * 4);
            a = fmaf(xv.x, wv.x, a);
            a = fmaf(xv.y, wv.y, a);
            a = fmaf(xv.z, wv.z, a);
            a = fmaf(xv.w, wv.w, a);
        }
    }

    part[(size_t)kblk * 384 + (size_t)(b0 + b) * 6 + j] = a;
}

// ---------------------------------------------------------------------------
// K1b (round-17, unchanged): ordered cross-block accumulation, latency-
// batched (64-wide register rounds; add order identical -> bit-exact).
// ---------------------------------------------------------------------------
__global__ __launch_bounds__(64)
void st_theta_final(const float* __restrict__ part, const float* __restrict__ bl,
                    float* __restrict__ theta)
{
#pragma clang fp contract(off)
    const int i = blockIdx.x * 64 + threadIdx.x;   // 0..383
    const int j = i % 6;
    const float* __restrict__ p = part + i;        // stride 384 per kblk

    float acc;
    {
        float r[64];
#pragma unroll
        for (int u = 0; u < 64; ++u) r[u] = p[(size_t)u * 384];
        acc = r[0];
#pragma unroll
        for (int u = 1; u < 64; ++u) acc = acc + r[u];
    }
    for (int base = 64; base < 768; base += 64) {
        float r[64];
#pragma unroll
        for (int u = 0; u < 64; ++u) r[u] = p[(size_t)(base + u) * 384];
#pragma unroll
        for (int u = 0; u < 64; ++u) acc = acc + r[u];
    }
    {
        float r[52];
#pragma unroll
        for (int u = 0; u < 52; ++u) r[u] = p[(size_t)(768 + u) * 384];
#pragma unroll
        for (int u = 0; u < 52; ++u) acc = acc + r[u];
    }
    theta[i] = acc + bl[j];
}

// ---------------------------------------------------------------------------
// K2 (round-22): round-16 arithmetic & 4-px/thread layout (measured best:
// 16 B/lane fully-packed loads/stores; r21's 8-px layout regressed via
// stride-32B lane patterns) + s_load theta (block-uniform pointer -> SGPRs;
// no LDS, no barrier; kernel has no ds_reads so SMEM lgkm mixing is free).
// Per-px fp32 replay byte-identical: med3 float-domain clip, float2 loads,
// cndmask select, numpy-order blend, contract off.
// ---------------------------------------------------------------------------
__global__ __launch_bounds__(256)
void st_sample(const float* __restrict__ x, const float* __restrict__ theta,
               float* __restrict__ out)
{
#pragma clang fp contract(off)
    const int blk = blockIdx.x;
    const int b   = blk >> 8;          // 256 blocks per batch
    const int rem = blk & 255;
    const int yo  = rem >> 1;
    const int seg = rem & 1;

    const float* __restrict__ tp = theta + b * 6;   // block-uniform -> s_load
    const float t00 = tp[0], t01 = tp[1], t02 = tp[2];
    const float t10 = tp[3], t11 = tp[4], t12 = tp[5];

    const int xo0 = seg * 1024 + threadIdx.x * 4;
    const float* __restrict__ img = x + (size_t)b * HW_;
    const float yof = (float)yo;

    const float cx1 = t01 * yof;
    const float cy1 = t11 * yof;

    nfloat4 o;
#pragma unroll
    for (int i = 0; i < 4; ++i) {
        const float xof = (float)(xo0 + i);
        const float px  = t00 * xof;
        const float sx  = px + cx1;
        const float xq  = sx + t02;
        const float py  = t10 * xof;
        const float sy  = py + cy1;
        const float yq  = sy + t12;

        const float xf0 = floorf(xq);
        const float yf0 = floorf(yq);

        const float x0f = __builtin_amdgcn_fmed3f(xf0,        0.f, 2047.f);
        const float x1f = __builtin_amdgcn_fmed3f(xf0 + 1.0f, 0.f, 2047.f);
        const float y0f = __builtin_amdgcn_fmed3f(yf0,        0.f,  127.f);
        const float y1f = __builtin_amdgcn_fmed3f(yf0 + 1.0f, 0.f,  127.f);

        const float basef = fminf(x0f, 2046.0f);
        const int base_i = (int)basef;
        const int y0c    = (int)y0f;
        const int y1c    = (int)y1f;

        const f2v v0 = *(const f2v*)(img + y0c * W_ + base_i);
        const f2v v1 = *(const f2v*)(img + y1c * W_ + base_i);

        const bool hiA = (x0f == 2047.0f);   // right clamp
        const bool loC = (x1f == basef);     // left clamp
        const float Ia = hiA ? v0.y : v0.x;
        const float Ic = loC ? v0.x : v0.y;
        const float Ib = hiA ? v1.y : v1.x;
        const float Id = loC ? v1.x : v1.y;

        const float gx = x1f - xq;
        const float fx = xq - x0f;
        const float gy = y1f - yq;
        const float fy = yq - y0f;

        const float wa = gx * gy;
        const float wb = gx * fy;
        const float wc = fx * gy;
        const float wd = fx * fy;

        const float pa = wa * Ia;
        const float pb = wb * Ib;
        const float s1 = pa + pb;
        const float pc = wc * Ic;
        const float s2 = s1 + pc;
        const float pd = wd * Id;
        o[i] = s2 + pd;
    }

    const size_t oidx = ((size_t)b * OH_ + yo) * OW_ + xo0;
    __builtin_nontemporal_store(o, (nfloat4*)(out + oidx));
}

extern "C" void kernel_launch(void* const* d_in, const int* in_sizes, int n_in,
                              void* d_out, int out_size, void* d_ws, size_t ws_size,
                              hipStream_t stream)
{
    const float* x  = (const float*)d_in[0];
    const float* w  = (const float*)d_in[1];
    const float* bl = (const float*)d_in[2];
    float* out = (float*)d_out;

    // d_out doubles as the 1.26 MB block-sum scratch (820*384 floats), fully
    // consumed by st_theta_final before st_sample overwrites every element.
    float* part  = (float*)d_out;
    float* theta = (float*)d_ws;    // 384 floats

    st_block_sums<<<NBLK * 2, 192, 0, stream>>>(x, w, part);
    st_theta_final<<<6, 64, 0, stream>>>(part, bl, theta);
    st_sample<<<B_ * OH_ * 2, 256, 0, stream>>>(x, theta, out);
}

// Round 23
// 61.372 us; speedup vs baseline: 1.9269x; 1.1083x over previous
//
#include <hip/hip_runtime.h>

#define B_   64
#define H_   128
#define W_   2048
#define HW_  (H_ * W_)        // 262144
#define OH_  128
#define OW_  2048

typedef float nfloat4 __attribute__((ext_vector_type(4)));
typedef float f2v __attribute__((ext_vector_type(2), aligned(4)));

// OpenBLAS sgemm emulation — SkylakeX params (VERIFIED bit-exact in round 6):
//   SGEMM_DEFAULT_Q = 320; K = 262144 -> blocks 0..817 len 320,
//   blk 818: off 261760 len 192; blk 819: off 261952 len 192.
//   Per C element: single sequential FMA chain over k within each block;
//   cross-block C += S_blk ascending; + b_loc in fp32.
// !!! The per-(blk,b,j) fmaf sequence and the K2 fp32 replay are bit-locked —
// !!! optimizations may only change load mechanics / parallel mapping.
#define QBLK 320
#define NBLK 820

__device__ __forceinline__ int blk_off(int blk) {
    if (blk <= 818) return blk * QBLK;    // 818*320 = 261760
    return 261952;                        // blk 819
}
__device__ __forceinline__ int blk_len(int blk) {
    return (blk < 818) ? 320 : 192;
}

// ---------------------------------------------------------------------------
// K1 (round-17 exact — best measured variant, ~33 us across 7 structural
// alternatives; see journal r8-r20). 1640 blocks x 192 thr; block = (kblk,
// 32-row half); thread = (j, b). x staged via global_load_lds w=16 into
// stride-81 rows (81 == 1 mod 8: bank-group spread); w reg-batched ->
// transposed LDS. Chain = exact k-ascending fmaf sequence.
// part layout: [kblk][b*6+j].
// ---------------------------------------------------------------------------
#define XSTR 81
__global__ __launch_bounds__(192)
void st_block_sums(const float* __restrict__ x, const float* __restrict__ w,
                   float* __restrict__ part)
{
    __shared__ float4 xs4[32 * XSTR];    // 41472 B
    __shared__ float  wt[6 * QBLK];      //  7680 B  (48.0 KB total)
    const int kblk = blockIdx.x >> 1;
    const int half = blockIdx.x & 1;
    const int tid  = threadIdx.x;

    const int off = blk_off(kblk);
    const int len = blk_len(kblk);       // 320 or 192
    const int nt4 = len >> 2;            // 80 or 48
    const int b0  = half * 32;

    const int widx = tid >> 6;           // wave 0..2
    const int lane = tid & 63;

#pragma unroll
    for (int i = 0; i < 14; ++i) {
        const int base = i * 192 + widx * 64;     // wave-uniform slot base
        if (base < 32 * XSTR) {                   // uniform per wave
            const int idx = base + lane;
            if (idx < 32 * XSTR) {                // EXEC mask (last chunk)
                const int r  = idx / XSTR;
                const int f4 = idx % XSTR;
                const int ug = (f4 < nt4) ? f4 : 0;   // pad -> harmless src
                const float* gp = x + (size_t)(b0 + r) * HW_ + off + ug * 4;
                __builtin_amdgcn_global_load_lds(
                    (const __attribute__((address_space(1))) unsigned int*)gp,
                    (__attribute__((address_space(3))) unsigned int*)&xs4[base],
                    16, 0, 0);
            }
        }
    }

    float wreg[10];
#pragma unroll
    for (int i = 0; i < 10; ++i) {
        const int e = tid + i * 192;
        wreg[i] = (e < 6 * len) ? w[(size_t)off * 6 + e] : 0.f;
    }
#pragma unroll
    for (int i = 0; i < 10; ++i) {
        const int e = tid + i * 192;
        if (e < 6 * len) wt[(e % 6) * QBLK + (e / 6)] = wreg[i];
    }
    __syncthreads();   // drains global_load_lds (vmcnt) + ds_writes

    const int j = tid >> 5;              // 0..5 (2 j per wave)
    const int b = tid & 31;              // row within half

    const float4* __restrict__ xr = xs4 + b * XSTR;
    const float*  __restrict__ wr = wt + j * QBLK;

    float a = 0.f;
    if (nt4 == 80) {
#pragma unroll
        for (int t4 = 0; t4 < 80; ++t4) {
            const float4 xv = xr[t4];
            const float4 wv = *(const float4*)(wr + t4 * 4);
            a = fmaf(xv.x, wv.x, a);
            a = fmaf(xv.y, wv.y, a);
            a = fmaf(xv.z, wv.z, a);
            a = fmaf(xv.w, wv.w, a);
        }
    } else {
#pragma unroll
        for (int t4 = 0; t4 < 48; ++t4) {
            const float4 xv = xr[t4];
            const float4 wv = *(const float4*)(wr + t4 * 4);
            a = fmaf(xv.x, wv.x, a);
            a = fmaf(xv.y, wv.y, a);
            a = fmaf(xv.z, wv.z, a);
            a = fmaf(xv.w, wv.w, a);
        }
    }

    part[(size_t)kblk * 384 + (size_t)(b0 + b) * 6 + j] = a;
}

// ---------------------------------------------------------------------------
// K1b (round-17, unchanged): ordered cross-block accumulation, latency-
// batched (64-wide register rounds; add order identical -> bit-exact).
// ---------------------------------------------------------------------------
__global__ __launch_bounds__(64)
void st_theta_final(const float* __restrict__ part, const float* __restrict__ bl,
                    float* __restrict__ theta)
{
#pragma clang fp contract(off)
    const int i = blockIdx.x * 64 + threadIdx.x;   // 0..383
    const int j = i % 6;
    const float* __restrict__ p = part + i;        // stride 384 per kblk

    float acc;
    {
        float r[64];
#pragma unroll
        for (int u = 0; u < 64; ++u) r[u] = p[(size_t)u * 384];
        acc = r[0];
#pragma unroll
        for (int u = 1; u < 64; ++u) acc = acc + r[u];
    }
    for (int base = 64; base < 768; base += 64) {
        float r[64];
#pragma unroll
        for (int u = 0; u < 64; ++u) r[u] = p[(size_t)(base + u) * 384];
#pragma unroll
        for (int u = 0; u < 64; ++u) acc = acc + r[u];
    }
    {
        float r[52];
#pragma unroll
        for (int u = 0; u < 52; ++u) r[u] = p[(size_t)(768 + u) * 384];
#pragma unroll
        for (int u = 0; u < 52; ++u) acc = acc + r[u];
    }
    theta[i] = acc + bl[j];
}

// ---------------------------------------------------------------------------
// K2 (round-23): round-22 kernel + XCD-AWARE BLOCK SWIZZLE (T1).
// Default dispatch round-robins the 256 blocks of one image across all 8
// XCDs -> 8x redundant L2 fills, L3-latency gathers. Chunked swizzle
// swz = (blk&7)*2048 + blk>>3 (bijective: 16384 % 8 == 0) gives XCD k a
// contiguous range = images 8k..8k+7; instantaneous working set ~1-2 MB
// fits the 4 MB XCD L2 -> gathers become L2 hits.
// Per-px fp32 replay byte-identical (med3 clip, float2+cndmask, numpy-order
// blend, contract off); s_load theta.
// ---------------------------------------------------------------------------
__global__ __launch_bounds__(256)
void st_sample(const float* __restrict__ x, const float* __restrict__ theta,
               float* __restrict__ out)
{
#pragma clang fp contract(off)
    // XCD-chunked bijective swizzle: grid 16384 = 8 * 2048.
    const int swz = (blockIdx.x & 7) * 2048 + (blockIdx.x >> 3);
    const int b   = swz >> 8;          // 256 blocks per batch
    const int rem = swz & 255;
    const int yo  = rem >> 1;
    const int seg = rem & 1;

    const float* __restrict__ tp = theta + b * 6;   // block-uniform -> s_load
    const float t00 = tp[0], t01 = tp[1], t02 = tp[2];
    const float t10 = tp[3], t11 = tp[4], t12 = tp[5];

    const int xo0 = seg * 1024 + threadIdx.x * 4;
    const float* __restrict__ img = x + (size_t)b * HW_;
    const float yof = (float)yo;

    const float cx1 = t01 * yof;
    const float cy1 = t11 * yof;

    nfloat4 o;
#pragma unroll
    for (int i = 0; i < 4; ++i) {
        const float xof = (float)(xo0 + i);
        const float px  = t00 * xof;
        const float sx  = px + cx1;
        const float xq  = sx + t02;
        const float py  = t10 * xof;
        const float sy  = py + cy1;
        const float yq  = sy + t12;

        const float xf0 = floorf(xq);
        const float yf0 = floorf(yq);

        const float x0f = __builtin_amdgcn_fmed3f(xf0,        0.f, 2047.f);
        const float x1f = __builtin_amdgcn_fmed3f(xf0 + 1.0f, 0.f, 2047.f);
        const float y0f = __builtin_amdgcn_fmed3f(yf0,        0.f,  127.f);
        const float y1f = __builtin_amdgcn_fmed3f(yf0 + 1.0f, 0.f,  127.f);

        const float basef = fminf(x0f, 2046.0f);
        const int base_i = (int)basef;
        const int y0c    = (int)y0f;
        const int y1c    = (int)y1f;

        const f2v v0 = *(const f2v*)(img + y0c * W_ + base_i);
        const f2v v1 = *(const f2v*)(img + y1c * W_ + base_i);

        const bool hiA = (x0f == 2047.0f);   // right clamp
        const bool loC = (x1f == basef);     // left clamp
        const float Ia = hiA ? v0.y : v0.x;
        const float Ic = loC ? v0.x : v0.y;
        const float Ib = hiA ? v1.y : v1.x;
        const float Id = loC ? v1.x : v1.y;

        const float gx = x1f - xq;
        const float fx = xq - x0f;
        const float gy = y1f - yq;
        const float fy = yq - y0f;

        const float wa = gx * gy;
        const float wb = gx * fy;
        const float wc = fx * gy;
        const float wd = fx * fy;

        const float pa = wa * Ia;
        const float pb = wb * Ib;
        const float s1 = pa + pb;
        const float pc = wc * Ic;
        const float s2 = s1 + pc;
        const float pd = wd * Id;
        o[i] = s2 + pd;
    }

    const size_t oidx = ((size_t)b * OH_ + yo) * OW_ + xo0;
    __builtin_nontemporal_store(o, (nfloat4*)(out + oidx));
}

extern "C" void kernel_launch(void* const* d_in, const int* in_sizes, int n_in,
                              void* d_out, int out_size, void* d_ws, size_t ws_size,
                              hipStream_t stream)
{
    const float* x  = (const float*)d_in[0];
    const float* w  = (const float*)d_in[1];
    const float* bl = (const float*)d_in[2];
    float* out = (float*)d_out;

    // d_out doubles as the 1.26 MB block-sum scratch (820*384 floats), fully
    // consumed by st_theta_final before st_sample overwrites every element.
    float* part  = (float*)d_out;
    float* theta = (float*)d_ws;    // 384 floats

    st_block_sums<<<NBLK * 2, 192, 0, stream>>>(x, w, part);
    st_theta_final<<<6, 64, 0, stream>>>(part, bl, theta);
    st_sample<<<B_ * OH_ * 2, 256, 0, stream>>>(x, theta, out);
}